// Round 12
// baseline (20.803 us; speedup 1.0000x reference)
//
#include <hip/hip_runtime.h>
#include <math.h>

// ---- problem constants ----
// SIZE=(60,270,480); CHANNELS=14; GRIDS: (60,16,16,8),(30,8,8,4),(15,4,4,2)
// IDX_MAX=(60,3,5) -> patch=(1,90,96); PADDING=(0,1,1) -> ppad=(1,92,98)
// t_embed: [64][1][92][98][14] = 8,078,336 f32 ; t_manip: [64][16]

#define N_PATCH 64
#define PPAD_H 92
#define PPAD_W 98
#define CH 14
#define ELEMS_PER_ROW (PPAD_W * CH)            // 1372 floats  = 343 float4
#define F4_PER_ROW (ELEMS_PER_ROW / 4)         // 343
#define ELEMS_PER_PATCH (PPAD_H * ELEMS_PER_ROW)   // 126224
#define F4_PER_PATCH (ELEMS_PER_PATCH / 4)     // 31556
#define TOTAL_EMBED (N_PATCH * ELEMS_PER_PATCH)
#define TOTAL_MANIP (N_PATCH * 16)

// V-record per row (floats): L0 [0,48)=6cells*8ch, L1 [48,64)=4*4, L2 [64,70)=3*2
#define RB_STRIDE 72                           // padded, 16B-aligned rows
#define L1_OFF 48
#define L2_OFF 64
#define ROWS_TOTAL (N_PATCH * PPAD_H)          // 5888
#define V_TOTAL (ROWS_TOTAL * 70)              // 412160 = 1610 * 256 exact
#define WS_PATCH (PPAD_H * RB_STRIDE)          // 6624 floats per patch

__device__ __forceinline__ float lerpf(float a, float b, float f) {
    return a + f * (b - a);
}

__device__ __forceinline__ int wcell0(int rw0, float sw, int Wg) {
    float x = ((float)rw0 + 0.5f) * sw - 0.5f;
    int w0 = (int)floorf(x);
    return min(max(w0, 0), Wg - 1);
}

#define SW0 ((float)((double)16 / 480.0))
#define SW1 ((float)((double)8  / 480.0))
#define SW2 ((float)((double)4  / 480.0))
#define SH0 ((float)((double)16 / 270.0))
#define SH1 ((float)((double)8  / 270.0))
#define SH2 ((float)((double)4  / 270.0))

// ---------- Kernel A: build all V tables into ws (no LDS, no barriers) ----------
__global__ __launch_bounds__(256) void vtab_kernel(
    const int* __restrict__ idx,
    const float* __restrict__ g0,
    const float* __restrict__ g1,
    const float* __restrict__ g2,
    float* __restrict__ ws,
    float* __restrict__ out)
{
    int bx = blockIdx.x;
    int tid = threadIdx.x;

    if (bx >= 1610) {   // ---- manip tail blocks ----
        int e = (bx - 1610) * 256 + tid;
        if (e < TOTAL_MANIP) {
            int nn = e >> 4;
            int j  = e & 15;
            int l  = j & 7;
            float base = (float)M_PI * (float)(1 << l);  // fl32(2^l*pi), pow2 exact
            float v = (float)idx[3 * nn + 0] * base;     // f32 mul = reference
            double dv = (double)v;
            out[TOTAL_EMBED + e] = (float)((j < 8) ? sin(dv) : cos(dv));
        }
        return;
    }

    int T = bx * 256 + tid;                    // < 412160
    int n   = T / (PPAD_H * 70);               // /6440
    int rem = T - n * (PPAD_H * 70);
    int row = rem / 70;
    int off = rem - row * 70;

    int it = idx[3 * n + 0];
    int ih = idx[3 * n + 1];
    int iw = idx[3 * n + 2];
    int rw0 = iw * 96 - 1;
    int rh  = ih * 90 + row - 1;
    float mh = ((unsigned)rh < 270u) ? 1.0f : 0.0f;
    float v;

    if (off < L1_OFF) {
        // L0: 6 cells x 8 ch; T identity (t = it exactly), h-lerp only
        int C0 = wcell0(rw0, SW0, 16);
        int cell = off >> 3, chn = off & 7;
        float xh = ((float)rh + 0.5f) * SH0 - 0.5f;
        float ff = floorf(xh);
        float fh = xh - ff;
        int h0 = (int)ff;
        int h0c = min(max(h0, 0), 15), h1c = min(h0 + 1, 15);
        int cw = min(C0 + cell, 15);
        const float* base = g0 + (size_t)it * 2048;
        float a = base[(h0c * 16 + cw) * 8 + chn];
        float b = base[(h1c * 16 + cw) * 8 + chn];
        v = mh * lerpf(a, b, fh);
    } else if (off < L2_OFF) {
        // L1: 4 cells x 4 ch; t-lerp + h-lerp
        int C0 = wcell0(rw0, SW1, 8);
        int o = off - L1_OFF;
        int cell = o >> 2, chn = o & 3;
        float xh = ((float)rh + 0.5f) * SH1 - 0.5f;
        float ff = floorf(xh);
        float fh = xh - ff;
        int h0 = (int)ff;
        int h0c = min(max(h0, 0), 7), h1c = min(h0 + 1, 7);
        float xt = ((float)it + 0.5f) * 0.5f - 0.5f;   // 30/60 exact
        float ftf = floorf(xt);
        float ft  = xt - ftf;
        int t0 = (int)ftf;
        int t0c = min(max(t0, 0), 29), t1c = min(t0 + 1, 29);
        int cw = min(C0 + cell, 7);
        float a00 = g1[((t0c * 8 + h0c) * 8 + cw) * 4 + chn];
        float a01 = g1[((t0c * 8 + h1c) * 8 + cw) * 4 + chn];
        float a10 = g1[((t1c * 8 + h0c) * 8 + cw) * 4 + chn];
        float a11 = g1[((t1c * 8 + h1c) * 8 + cw) * 4 + chn];
        v = mh * lerpf(lerpf(a00, a01, fh), lerpf(a10, a11, fh), ft);
    } else {
        // L2: 3 cells x 2 ch
        int C0 = wcell0(rw0, SW2, 4);
        int o = off - L2_OFF;
        int cell = o >> 1, chn = o & 1;
        float xh = ((float)rh + 0.5f) * SH2 - 0.5f;
        float ff = floorf(xh);
        float fh = xh - ff;
        int h0 = (int)ff;
        int h0c = min(max(h0, 0), 3), h1c = min(h0 + 1, 3);
        float xt = ((float)it + 0.5f) * 0.25f - 0.5f;  // 15/60 exact
        float ftf = floorf(xt);
        float ft  = xt - ftf;
        int t0 = (int)ftf;
        int t0c = min(max(t0, 0), 14), t1c = min(t0 + 1, 14);
        int cw = min(C0 + cell, 3);
        float a00 = g2[((t0c * 4 + h0c) * 4 + cw) * 2 + chn];
        float a01 = g2[((t0c * 4 + h1c) * 4 + cw) * 2 + chn];
        float a10 = g2[((t1c * 4 + h0c) * 4 + cw) * 2 + chn];
        float a11 = g2[((t1c * 4 + h1c) * 4 + cw) * 2 + chn];
        v = mh * lerpf(lerpf(a00, a01, fh), lerpf(a10, a11, fh), ft);
    }
    ws[n * WS_PATCH + row * RB_STRIDE + off] = v;
}

// ---------- Kernel B: pure streaming w-lerp + coalesced float4 stores ----------
__device__ __forceinline__ void do_pair(int P, int iw, int C0_0, int C0_1, int C0_2,
                                        const float* __restrict__ V,
                                        float& rx, float& ry)
{
    int q = P % 7;                 // u24 ops (P < 686)
    int p = P / 7;                 // pixel within row, 0..97
    int rw = iw * 96 + p - 1;
    float mw = ((unsigned)rw < 480u) ? 1.0f : 0.0f;
    int lvl = (q >= 4) + (q >= 6);

    float sw = (lvl == 0) ? SW0 : ((lvl == 1) ? SW1 : SW2);
    int Wg1  = (16 >> lvl) - 1;                    // 15,7,3
    int cs   = 8 >> lvl;                           // 8,4,2
    int bb   = (lvl == 0) ? 0 : ((lvl == 1) ? L1_OFF : L2_OFF);
    int ch   = 2 * q - ((lvl == 0) ? 0 : ((lvl == 1) ? 8 : 12));
    int C0   = (lvl == 0) ? C0_0 : ((lvl == 1) ? C0_1 : C0_2);

    float x = ((float)rw + 0.5f) * sw - 0.5f;
    float ffl = floorf(x);
    float fw = x - ffl;
    int w0 = (int)ffl;
    int wa = min(max(w0, 0), Wg1);
    int wb = min(w0 + 1, Wg1);
    int oA = bb + (wa - C0) * cs + ch;
    int oB = bb + (wb - C0) * cs + ch;
    float2 A = *(const float2*)(V + oA);
    float2 B = *(const float2*)(V + oB);
    rx = mw * lerpf(A.x, B.x, fw);
    ry = mw * lerpf(A.y, B.y, fw);
}

__global__ __launch_bounds__(384) void stream_kernel(
    const int* __restrict__ idx,
    const float* __restrict__ ws,
    float* __restrict__ out)
{
    const int row = blockIdx.x;            // 0..91
    const int n   = blockIdx.y;            // 0..63
    const int j   = threadIdx.x;
    if (j >= F4_PER_ROW) return;           // 343 active

    const int iw = idx[3 * n + 2];         // block-uniform -> scalar
    const int rw0 = iw * 96 - 1;
    const int C0_0 = wcell0(rw0, SW0, 16);
    const int C0_1 = wcell0(rw0, SW1, 8);
    const int C0_2 = wcell0(rw0, SW2, 4);
    const float* V = ws + n * WS_PATCH + row * RB_STRIDE;

    float r0x, r0y, r1x, r1y;
    do_pair(2 * j,     iw, C0_0, C0_1, C0_2, V, r0x, r0y);
    do_pair(2 * j + 1, iw, C0_0, C0_1, C0_2, V, r1x, r1y);

    float4* gb = (float4*)out + (size_t)n * F4_PER_PATCH + row * F4_PER_ROW + j;
    *gb = make_float4(r0x, r0y, r1x, r1y);
}

extern "C" void kernel_launch(void* const* d_in, const int* in_sizes, int n_in,
                              void* d_out, int out_size, void* d_ws, size_t ws_size,
                              hipStream_t stream) {
    const int*   idx = (const int*)  d_in[0];
    const float* g0  = (const float*)d_in[3];
    const float* g1  = (const float*)d_in[4];
    const float* g2  = (const float*)d_in[5];
    float* out = (float*)d_out;
    float* ws  = (float*)d_ws;

    // A: 1610 V-table blocks + 4 manip blocks, no barriers
    vtab_kernel<<<1614, 256, 0, stream>>>(idx, g0, g1, g2, ws, out);
    // B: pure streaming store kernel, no LDS, no barriers
    dim3 gridB(PPAD_H, N_PATCH);   // (92, 64)
    stream_kernel<<<gridB, 384, 0, stream>>>(idx, ws, out);
}

// Round 13
// 13.631 us; speedup vs baseline: 1.5261x; 1.5261x over previous
//
#include <hip/hip_runtime.h>
#include <math.h>

// ---- problem constants ----
// SIZE=(60,270,480); CHANNELS=14; GRIDS: (60,16,16,8),(30,8,8,4),(15,4,4,2)
// IDX_MAX=(60,3,5) -> patch=(1,90,96); PADDING=(0,1,1) -> ppad=(1,92,98)
// t_embed: [64][1][92][98][14] = 8,078,336 f32 ; t_manip: [64][16]

#define N_PATCH 64
#define PPAD_H 92
#define PPAD_W 98
#define CH 14
#define PIX_PER_PATCH (PPAD_H * PPAD_W)        // 9016
#define ELEMS_PER_PATCH (PIX_PER_PATCH * CH)   // 126224
#define ELEMS_PER_BLOCK (2 * PPAD_W * CH)      // 2744 (2 rows)
#define TOTAL_EMBED (N_PATCH * ELEMS_PER_PATCH)
#define TOTAL_MANIP (N_PATCH * 16)

// per-row V-record (floats): L0 [0,48)=6cells*8ch, L1 [48,64)=4*4, L2 [64,70)=3*2
#define RB_STRIDE 72
#define L1_OFF 48
#define L2_OFF 64

#define SW0 ((float)((double)16 / 480.0))
#define SW1 ((float)((double)8  / 480.0))
#define SW2 ((float)((double)4  / 480.0))
#define SH0 ((float)((double)16 / 270.0))
#define SH1 ((float)((double)8  / 270.0))
#define SH2 ((float)((double)4  / 270.0))

__device__ __forceinline__ float lerpf(float a, float b, float f) {
    return a + f * (b - a);
}

__device__ __forceinline__ int wcell0(int rw0, float sw, int Wg) {
    float x = ((float)rw0 + 0.5f) * sw - 0.5f;
    int w0 = (int)floorf(x);
    return min(max(w0, 0), Wg - 1);
}

__global__ __launch_bounds__(256) void embed_kernel(
    const int* __restrict__ idx,
    const float* __restrict__ g0,
    const float* __restrict__ g1,
    const float* __restrict__ g2,
    float* __restrict__ out)
{
    // wave-private LDS: no s_barrier anywhere in this kernel
    __shared__ __align__(16) float s_V[4][RB_STRIDE];   // 1.1 KB
    __shared__ __align__(16) float s_buf[4][704];       // 11 KB (50px*14 = 700 max)

    const int tid  = threadIdx.x;
    const int bx   = blockIdx.x;       // 0..45 (2 rows each)
    const int n    = blockIdx.y;       // 0..63
    const int wv   = tid >> 6;
    const int lane = tid & 63;

    const int it = idx[3 * n + 0];
    const int ih = idx[3 * n + 1];
    const int iw = idx[3 * n + 2];
    const int rw0 = iw * 96 - 1;

    const int C0_0 = wcell0(rw0, SW0, 16);
    const int C0_1 = wcell0(rw0, SW1, 8);
    const int C0_2 = wcell0(rw0, SW2, 4);

    // ---- fused manip (one block only) ----
    if (bx == 0 && n == 0) {
        float* om = out + TOTAL_EMBED;
        for (int e = tid; e < TOTAL_MANIP; e += 256) {
            int nn = e >> 4;
            int j  = e & 15;
            int l  = j & 7;
            float base = (float)M_PI * (float)(1 << l);  // fl32(2^l*pi), pow2 exact
            float v = (float)idx[3 * nn + 0] * base;     // f32 mul = reference
            double dv = (double)v;
            om[e] = (float)((j < 8) ? sin(dv) : cos(dv));
        }
    }

    // ---- wave partition: waves 0,1 -> block row 0; waves 2,3 -> block row 1 ----
    // px spans: w0:0-47, w1:48-97, w2:98-145, w3:146-195  (each within ONE row)
    const int rowloc = wv >> 1;
    const int ww0    = (wv & 1) * 48;
    const int npx    = 48 + 2 * (wv & 1);     // 48 or 50

    // ---- wave-uniform h/t-lerp params for this row ----
    const int rh = ih * 90 + bx * 2 + rowloc - 1;
    const float mh = ((unsigned)rh < 270u) ? 1.0f : 0.0f;
    const float rhc = (float)rh + 0.5f;

    float xh0 = rhc * SH0 - 0.5f;
    float fh0 = xh0 - floorf(xh0);
    int   h00 = (int)floorf(xh0);
    int   h0c0 = min(max(h00, 0), 15), h1c0 = min(h00 + 1, 15);

    float xh1 = rhc * SH1 - 0.5f;
    float fh1 = xh1 - floorf(xh1);
    int   h01 = (int)floorf(xh1);
    int   h0c1 = min(max(h01, 0), 7), h1c1 = min(h01 + 1, 7);

    float xh2 = rhc * SH2 - 0.5f;
    float fh2 = xh2 - floorf(xh2);
    int   h02 = (int)floorf(xh2);
    int   h0c2 = min(max(h02, 0), 3), h1c2 = min(h02 + 1, 3);

    float xt1 = ((float)it + 0.5f) * 0.5f - 0.5f;    // 30/60 exact
    float ft1 = xt1 - floorf(xt1);
    int   t01 = (int)floorf(xt1);
    int   t0c1 = min(max(t01, 0), 29), t1c1 = min(t01 + 1, 29);

    float xt2 = ((float)it + 0.5f) * 0.25f - 0.5f;   // 15/60 exact
    float ft2 = xt2 - floorf(xt2);
    int   t02 = (int)floorf(xt2);
    int   t0c2 = min(max(t02, 0), 14), t1c2 = min(t02 + 1, 14);

    // ---- build this wave's private 70-entry V record ----
    for (int e = lane; e < 70; e += 64) {
        float v;
        if (e < L1_OFF) {
            int cell = e >> 3, chn = e & 7;
            int cw = min(C0_0 + cell, 15);
            const float* b0 = g0 + (size_t)it * 2048;
            float a = b0[(h0c0 * 16 + cw) * 8 + chn];
            float b = b0[(h1c0 * 16 + cw) * 8 + chn];
            v = mh * lerpf(a, b, fh0);
        } else if (e < L2_OFF) {
            int o = e - L1_OFF;
            int cell = o >> 2, chn = o & 3;
            int cw = min(C0_1 + cell, 7);
            float a00 = g1[((t0c1 * 8 + h0c1) * 8 + cw) * 4 + chn];
            float a01 = g1[((t0c1 * 8 + h1c1) * 8 + cw) * 4 + chn];
            float a10 = g1[((t1c1 * 8 + h0c1) * 8 + cw) * 4 + chn];
            float a11 = g1[((t1c1 * 8 + h1c1) * 8 + cw) * 4 + chn];
            v = mh * lerpf(lerpf(a00, a01, fh1), lerpf(a10, a11, fh1), ft1);
        } else {
            int o = e - L2_OFF;
            int cell = o >> 1, chn = o & 1;
            int cw = min(C0_2 + cell, 3);
            float a00 = g2[((t0c2 * 4 + h0c2) * 4 + cw) * 2 + chn];
            float a01 = g2[((t0c2 * 4 + h1c2) * 4 + cw) * 2 + chn];
            float a10 = g2[((t1c2 * 4 + h0c2) * 4 + cw) * 2 + chn];
            float a11 = g2[((t1c2 * 4 + h1c2) * 4 + cw) * 2 + chn];
            v = mh * lerpf(lerpf(a00, a01, fh2), lerpf(a10, a11, fh2), ft2);
        }
        s_V[wv][e] = v;
    }

    // wave-local V visible: lgkmcnt drains ds_writes; no s_barrier needed
    asm volatile("s_waitcnt lgkmcnt(0)" ::: "memory");
    __builtin_amdgcn_sched_barrier(0);
    __builtin_amdgcn_wave_barrier();
    __builtin_amdgcn_sched_barrier(0);

    // ---- per-pixel compute (register w-LUT, identical math to R10) ----
    if (lane < npx) {
        int ww = ww0 + lane;
        int rw = iw * 96 + ww - 1;
        float mw = ((unsigned)rw < 480u) ? 1.0f : 0.0f;
        float rwc = (float)rw + 0.5f;

        float x0 = rwc * SW0 - 0.5f;
        float f0f = floorf(x0);
        float fw0 = x0 - f0f;
        int w00 = (int)f0f;
        int oA0 = (min(max(w00, 0), 15) - C0_0) * 8;
        int oB0 = (min(w00 + 1, 15)    - C0_0) * 8;
        float x1 = rwc * SW1 - 0.5f;
        float f1f = floorf(x1);
        float fw1 = x1 - f1f;
        int w01 = (int)f1f;
        int oA1 = L1_OFF + (min(max(w01, 0), 7) - C0_1) * 4;
        int oB1 = L1_OFF + (min(w01 + 1, 7)     - C0_1) * 4;
        float x2 = rwc * SW2 - 0.5f;
        float f2f = floorf(x2);
        float fw2 = x2 - f2f;
        int w02 = (int)f2f;
        int oA2 = L2_OFF + (min(max(w02, 0), 3) - C0_2) * 2;
        int oB2 = L2_OFF + (min(w02 + 1, 3)     - C0_2) * 2;

        const float* V = s_V[wv];
        float4 A0  = *(const float4*)(V + oA0);
        float4 A1  = *(const float4*)(V + oA0 + 4);
        float4 B0  = *(const float4*)(V + oB0);
        float4 B1  = *(const float4*)(V + oB0 + 4);
        float4 C1a = *(const float4*)(V + oA1);
        float4 C1b = *(const float4*)(V + oB1);
        float2 C2a = *(const float2*)(V + oA2);
        float2 C2b = *(const float2*)(V + oB2);

        float2* b = (float2*)(s_buf[wv] + lane * CH);
        b[0] = make_float2(mw * lerpf(A0.x, B0.x, fw0),
                           mw * lerpf(A0.y, B0.y, fw0));
        b[1] = make_float2(mw * lerpf(A0.z, B0.z, fw0),
                           mw * lerpf(A0.w, B0.w, fw0));
        b[2] = make_float2(mw * lerpf(A1.x, B1.x, fw0),
                           mw * lerpf(A1.y, B1.y, fw0));
        b[3] = make_float2(mw * lerpf(A1.z, B1.z, fw0),
                           mw * lerpf(A1.w, B1.w, fw0));
        b[4] = make_float2(mw * lerpf(C1a.x, C1b.x, fw1),
                           mw * lerpf(C1a.y, C1b.y, fw1));
        b[5] = make_float2(mw * lerpf(C1a.z, C1b.z, fw1),
                           mw * lerpf(C1a.w, C1b.w, fw1));
        b[6] = make_float2(mw * lerpf(C2a.x, C2b.x, fw2),
                           mw * lerpf(C2a.y, C2b.y, fw2));
    }

    asm volatile("s_waitcnt lgkmcnt(0)" ::: "memory");
    __builtin_amdgcn_sched_barrier(0);
    __builtin_amdgcn_wave_barrier();
    __builtin_amdgcn_sched_barrier(0);

    // ---- wave-local coalesced store of its own contiguous f4 range ----
    const int p0  = rowloc * PPAD_W + ww0;          // 0,48,98,146 (even)
    const int fb  = (p0 >> 1) * 7;                  // 0,168,343,511
    const int nf4 = (npx >> 1) * 7;                 // 168 or 175
    const float4* sb = (const float4*)s_buf[wv];
    float4* gb = (float4*)(out + (size_t)n * ELEMS_PER_PATCH
                               + (size_t)bx * ELEMS_PER_BLOCK) + fb;
    for (int j = lane; j < nf4; j += 64) gb[j] = sb[j];
}

extern "C" void kernel_launch(void* const* d_in, const int* in_sizes, int n_in,
                              void* d_out, int out_size, void* d_ws, size_t ws_size,
                              hipStream_t stream) {
    const int*   idx = (const int*)  d_in[0];
    const float* g0  = (const float*)d_in[3];
    const float* g1  = (const float*)d_in[4];
    const float* g2  = (const float*)d_in[5];
    float* out = (float*)d_out;

    dim3 grid(46, N_PATCH);   // 2944 blocks (empirical sweet spot), 0 s_barriers
    embed_kernel<<<grid, 256, 0, stream>>>(idx, g0, g1, g2, out);
}